// Round 9
// baseline (327.940 us; speedup 1.0000x reference)
//
#include <hip/hip_runtime.h>
#include <hip/hip_bf16.h>

#define N_NODES 50000
#define N_EDGES 800000
#define NUM_GRAPHS 256
#define D 64
#define EPS 1e-5f
#define N_PART 8
#define PART_SIZE (N_NODES / N_PART)   // 6250
#define SCAT_CHUNKS 512

// ---------------------------------------------------------------------------
// 1) one-pass slotted-CSR build, XCD-partitioned by destination range.
//    Block b: partition p = b&7 (round-robin block->XCD heuristic keeps each
//    dest range's stores+atomics in ONE XCD's L2), chunk = b>>3 over edges.
__global__ __launch_bounds__(256) void scatter_cnt_kernel(
        const int* __restrict__ ei, int* __restrict__ cnt,
        int* __restrict__ ssrc, int cap, int E) {
    int p     = blockIdx.x & (N_PART - 1);
    int chunk = blockIdx.x >> 3;
    int per   = (E + SCAT_CHUNKS - 1) / SCAT_CHUNKS;
    int lo    = chunk * per;
    int hi    = lo + per; if (hi > E) hi = E;
    for (int e = lo + threadIdx.x; e < hi; e += 256) {
        int c = ei[E + e];
        if (c / PART_SIZE == p) {
            int r = ei[e];
            int pos = atomicAdd(&cnt[c], 1);
            if (pos < cap) ssrc[(size_t)c * cap + pos] = r;  // P(overflow)~1e-20
        }
    }
}

// 2) Y[N,64] = X[N,64] @ W[64,64] — 64-row tile per block, 4x4 register blocking.
__global__ __launch_bounds__(256) void gemm64_kernel(const float* __restrict__ X,
                                                     const float* __restrict__ W,
                                                     float* __restrict__ Y, int N) {
    __shared__ float Ws[64 * 64];     // row k, col c
    __shared__ float Xs[64 * 65];     // row r (padded), col k
    int base = blockIdx.x * 64;
    for (int i = threadIdx.x; i < 1024; i += 256)
        ((float4*)Ws)[i] = ((const float4*)W)[i];
    for (int i = threadIdx.x; i < 1024; i += 256) {
        int rr = i >> 4, cc = (i & 15) * 4;
        float4 xv = (base + rr < N)
            ? ((const float4*)X)[(size_t)(base + rr) * 16 + (i & 15)]
            : make_float4(0.f, 0.f, 0.f, 0.f);
        float* dst = &Xs[rr * 65 + cc];
        dst[0] = xv.x; dst[1] = xv.y; dst[2] = xv.z; dst[3] = xv.w;
    }
    __syncthreads();
    int rg = (threadIdx.x >> 4) * 4;        // rows rg..rg+3
    int cg = (threadIdx.x & 15) * 4;        // cols cg..cg+3
    float4 a0 = make_float4(0.f,0.f,0.f,0.f);
    float4 a1 = a0, a2 = a0, a3 = a0;
#pragma unroll
    for (int k = 0; k < 64; k++) {
        float4 wv = *(const float4*)&Ws[k * 64 + cg];
        float x0 = Xs[(rg + 0) * 65 + k];
        float x1 = Xs[(rg + 1) * 65 + k];
        float x2 = Xs[(rg + 2) * 65 + k];
        float x3 = Xs[(rg + 3) * 65 + k];
        a0.x += x0*wv.x; a0.y += x0*wv.y; a0.z += x0*wv.z; a0.w += x0*wv.w;
        a1.x += x1*wv.x; a1.y += x1*wv.y; a1.z += x1*wv.z; a1.w += x1*wv.w;
        a2.x += x2*wv.x; a2.y += x2*wv.y; a2.z += x2*wv.z; a2.w += x2*wv.w;
        a3.x += x3*wv.x; a3.y += x3*wv.y; a3.z += x3*wv.z; a3.w += x3*wv.w;
    }
    if (base + rg + 3 < N) {
        *((float4*)&Y[(size_t)(base + rg + 0) * 64 + cg]) = a0;
        *((float4*)&Y[(size_t)(base + rg + 1) * 64 + cg]) = a1;
        *((float4*)&Y[(size_t)(base + rg + 2) * 64 + cg]) = a2;
        *((float4*)&Y[(size_t)(base + rg + 3) * 64 + cg]) = a3;
    } else {
        if (base + rg + 0 < N) *((float4*)&Y[(size_t)(base + rg + 0) * 64 + cg]) = a0;
        if (base + rg + 1 < N) *((float4*)&Y[(size_t)(base + rg + 1) * 64 + cg]) = a1;
        if (base + rg + 2 < N) *((float4*)&Y[(size_t)(base + rg + 2) * 64 + cg]) = a2;
        if (base + rg + 3 < N) *((float4*)&Y[(size_t)(base + rg + 3) * 64 + cg]) = a3;
    }
}

// 3) fused slotted-CSR aggregation + self-loop + gcn bias + BN + ReLU.
//    One wave per destination node. Lane = (edge-sub 0..7, col-group 0..7 of 8):
//    8 edges in flight per wave (2x the previous MLP), 2 float4 gathers/lane/edge.
//    dinv folded in as rsqrtf(cnt+1) — dinv table & kernel deleted.
__global__ __launch_bounds__(256) void agg_bn_kernel(
        const float* __restrict__ xw, const int* __restrict__ cnt,
        const int* __restrict__ ssrc, int cap,
        const float* __restrict__ b, const float* __restrict__ g,
        const float* __restrict__ bb, const float* __restrict__ m,
        const float* __restrict__ var,
        float* __restrict__ out, int N) {
    int wave = (blockIdx.x * blockDim.x + threadIdx.x) >> 6;
    int lane = threadIdx.x & 63;
    if (wave >= N) return;
    int c   = wave;
    int sub = lane >> 3;        // which of 8 concurrent edges
    int f2  = lane & 7;         // col block: float4 indices 2*f2, 2*f2+1
    const float4* xw4 = (const float4*)xw;
    int n = cnt[c];
    if (n > cap) n = cap;
    size_t base = (size_t)c * cap;
    float dc = rsqrtf((float)n + 1.0f);
    float4 accA = make_float4(0.f, 0.f, 0.f, 0.f);
    float4 accB = accA;
    if (sub == 0) {  // self-loop term dc*xw[c] (final *dc applied below)
        float4 xa = xw4[(size_t)c * 16 + 2 * f2];
        float4 xb = xw4[(size_t)c * 16 + 2 * f2 + 1];
        accA.x = dc * xa.x; accA.y = dc * xa.y; accA.z = dc * xa.z; accA.w = dc * xa.w;
        accB.x = dc * xb.x; accB.y = dc * xb.y; accB.z = dc * xb.z; accB.w = dc * xb.w;
    }
    for (int e0 = 0; e0 < n; e0 += 8) {
        int e = e0 + sub;
        if (e < n) {
            int   r = ssrc[base + e];
            float w = rsqrtf((float)cnt[r] + 1.0f);
            float4 xa = xw4[(size_t)r * 16 + 2 * f2];
            float4 xb = xw4[(size_t)r * 16 + 2 * f2 + 1];
            accA.x += w * xa.x; accA.y += w * xa.y;
            accA.z += w * xa.z; accA.w += w * xa.w;
            accB.x += w * xb.x; accB.y += w * xb.y;
            accB.z += w * xb.z; accB.w += w * xb.w;
        }
    }
    // reduce the 8 sub-accumulators (lanes differing in bits 3,4,5)
#pragma unroll
    for (int off = 8; off < 64; off <<= 1) {
        accA.x += __shfl_xor(accA.x, off, 64); accA.y += __shfl_xor(accA.y, off, 64);
        accA.z += __shfl_xor(accA.z, off, 64); accA.w += __shfl_xor(accA.w, off, 64);
        accB.x += __shfl_xor(accB.x, off, 64); accB.y += __shfl_xor(accB.y, off, 64);
        accB.z += __shfl_xor(accB.z, off, 64); accB.w += __shfl_xor(accB.w, off, 64);
    }
    if (sub == 0) {
        const float4* b4v  = (const float4*)b;
        const float4* m4v  = (const float4*)m;
        const float4* v4v  = (const float4*)var;
        const float4* g4v  = (const float4*)g;
        const float4* bb4v = (const float4*)bb;
#pragma unroll
        for (int half = 0; half < 2; half++) {
            int i4 = 2 * f2 + half;
            float4 acc = half ? accB : accA;
            float4 b4 = b4v[i4], m4 = m4v[i4], v4 = v4v[i4], g4 = g4v[i4], bb4 = bb4v[i4];
            float4 h;
            h.x = (acc.x * dc + b4.x - m4.x) * (1.0f / sqrtf(v4.x + EPS)) * g4.x + bb4.x;
            h.y = (acc.y * dc + b4.y - m4.y) * (1.0f / sqrtf(v4.y + EPS)) * g4.y + bb4.y;
            h.z = (acc.z * dc + b4.z - m4.z) * (1.0f / sqrtf(v4.z + EPS)) * g4.z + bb4.z;
            h.w = (acc.w * dc + b4.w - m4.w) * (1.0f / sqrtf(v4.w + EPS)) * g4.w + bb4.w;
            h.x = h.x > 0.f ? h.x : 0.f;
            h.y = h.y > 0.f ? h.y : 0.f;
            h.z = h.z > 0.f ? h.z : 0.f;
            h.w = h.w > 0.f ? h.w : 0.f;
            ((float4*)out)[(size_t)c * 16 + i4] = h;
        }
    }
}

// 4) fused mean-pool (via sorted-batch binary search) + full MLP head.
__global__ __launch_bounds__(256) void pool_head_kernel(
        const float* __restrict__ h, const int* __restrict__ batch,
        const float* __restrict__ hW1, const float* __restrict__ hb1,
        const float* __restrict__ hg1, const float* __restrict__ hbb1,
        const float* __restrict__ hm1, const float* __restrict__ hv1,
        const float* __restrict__ hW2, const float* __restrict__ hb2,
        const float* __restrict__ hg2, const float* __restrict__ hbb2,
        const float* __restrict__ hm2, const float* __restrict__ hv2,
        const float* __restrict__ hW3, const float* __restrict__ hb3,
        const float* __restrict__ hW4, const float* __restrict__ hb4,
        float* __restrict__ out) {
    __shared__ int se[2];
    __shared__ float red[256];
    __shared__ float pooled[64];
    __shared__ float z1[256];
    __shared__ float z2[128];
    __shared__ float z3[64];
    int g = blockIdx.x;
    int t = threadIdx.x;
    if (t < 2) {
        int target = g + t;
        int lo = 0, hi = N_NODES;
        while (lo < hi) {
            int mid = (lo + hi) >> 1;
            if (batch[mid] < target) lo = mid + 1; else hi = mid;
        }
        se[t] = lo;
    }
    __syncthreads();
    int start = se[0], end = se[1];
    {   // mean pool: 4 row-groups x 64 features
        int f = t & 63, rg = t >> 6;
        float part = 0.0f;
        for (int r = start + rg; r < end; r += 4) part += h[(size_t)r * 64 + f];
        red[t] = part;
        __syncthreads();
        if (t < 64) {
            float s = red[t] + red[t + 64] + red[t + 128] + red[t + 192];
            float cnt = (float)(end - start);
            cnt = cnt > 1.0f ? cnt : 1.0f;
            pooled[t] = s / cnt;
        }
    }
    __syncthreads();
    {   // layer 1: 64 -> 256, BN + relu
        float acc = hb1[t];
#pragma unroll
        for (int k = 0; k < 64; k++) acc += pooled[k] * hW1[k * 256 + t];
        acc = (acc - hm1[t]) * (1.0f / sqrtf(hv1[t] + EPS)) * hg1[t] + hbb1[t];
        z1[t] = acc > 0.0f ? acc : 0.0f;
    }
    __syncthreads();
    if (t < 128) {  // layer 2: 256 -> 128, BN + relu
        float acc = hb2[t];
#pragma unroll 8
        for (int k = 0; k < 256; k++) acc += z1[k] * hW2[k * 128 + t];
        acc = (acc - hm2[t]) * (1.0f / sqrtf(hv2[t] + EPS)) * hg2[t] + hbb2[t];
        z2[t] = acc > 0.0f ? acc : 0.0f;
    }
    __syncthreads();
    if (t < 64) {   // layer 3: 128 -> 64, relu
        float acc = hb3[t];
#pragma unroll 8
        for (int k = 0; k < 128; k++) acc += z2[k] * hW3[k * 64 + t];
        z3[t] = acc > 0.0f ? acc : 0.0f;
    }
    __syncthreads();
    if (t < 64) {   // layer 4: 64 -> 1, wave reduce
        float v = z3[t] * hW4[t];
        for (int off = 32; off > 0; off >>= 1) v += __shfl_down(v, off, 64);
        if (t == 0) out[g] = v + hb4[0];
    }
}

extern "C" void kernel_launch(void* const* d_in, const int* in_sizes, int n_in,
                              void* d_out, int out_size, void* d_ws, size_t ws_size,
                              hipStream_t stream) {
    const float* x     = (const float*)d_in[0];
    const int*   ei    = (const int*)d_in[1];   // [2, E] int32
    const int*   batch = (const int*)d_in[2];
    const float* W0 = (const float*)d_in[3];
    const float* b0 = (const float*)d_in[4];
    const float* g0 = (const float*)d_in[5];
    const float* bb0 = (const float*)d_in[6];
    const float* m0 = (const float*)d_in[7];
    const float* v0 = (const float*)d_in[8];
    const float* W1 = (const float*)d_in[9];
    const float* b1 = (const float*)d_in[10];
    const float* g1 = (const float*)d_in[11];
    const float* bb1 = (const float*)d_in[12];
    const float* m1 = (const float*)d_in[13];
    const float* v1 = (const float*)d_in[14];
    const float* hW1 = (const float*)d_in[15];
    const float* hb1 = (const float*)d_in[16];
    const float* hg1 = (const float*)d_in[17];
    const float* hbb1 = (const float*)d_in[18];
    const float* hm1 = (const float*)d_in[19];
    const float* hv1 = (const float*)d_in[20];
    const float* hW2 = (const float*)d_in[21];
    const float* hb2 = (const float*)d_in[22];
    const float* hg2 = (const float*)d_in[23];
    const float* hbb2 = (const float*)d_in[24];
    const float* hm2 = (const float*)d_in[25];
    const float* hv2 = (const float*)d_in[26];
    const float* hW3 = (const float*)d_in[27];
    const float* hb3 = (const float*)d_in[28];
    const float* hW4 = (const float*)d_in[29];
    const float* hb4 = (const float*)d_in[30];
    float* out = (float*)d_out;

    // workspace layout (4-byte elements; d_ws is 16B-aligned)
    float* bufA = (float*)d_ws;                          // N*64
    float* bufB = bufA + (size_t)N_NODES * D;            // N*64
    int*   cnt  = (int*)(bufB + (size_t)N_NODES * D);    // N
    int*   ssrc = cnt + N_NODES;                         // N*cap

    // pick the slot capacity from remaining workspace (prefer 64; deg~Poisson(16))
    size_t used  = ((size_t)2 * N_NODES * D + N_NODES) * 4;
    int cap = 64;
    if (ws_size >= used) {
        size_t avail = (ws_size - used) / ((size_t)N_NODES * 4);
        if (avail < (size_t)cap) cap = (int)avail & ~3;  // multiple of 4
    } else {
        cap = 0;  // should not happen; avoids OOB
    }

    const int NT = 256;
    hipMemsetAsync(cnt, 0, (size_t)N_NODES * 4, stream);

    // one-pass XCD-partitioned slotted-CSR build
    scatter_cnt_kernel<<<SCAT_CHUNKS * N_PART, NT, 0, stream>>>(ei, cnt, ssrc, cap, N_EDGES);

    // layer 0
    gemm64_kernel<<<(N_NODES + 63) / 64, NT, 0, stream>>>(x, W0, bufA, N_NODES);
    agg_bn_kernel<<<(N_NODES * 64 + NT - 1) / NT, NT, 0, stream>>>(
        bufA, cnt, ssrc, cap, b0, g0, bb0, m0, v0, bufB, N_NODES);

    // layer 1
    gemm64_kernel<<<(N_NODES + 63) / 64, NT, 0, stream>>>(bufB, W1, bufA, N_NODES);
    agg_bn_kernel<<<(N_NODES * 64 + NT - 1) / NT, NT, 0, stream>>>(
        bufA, cnt, ssrc, cap, b1, g1, bb1, m1, v1, bufB, N_NODES);

    // mean pool + MLP head (fused)
    pool_head_kernel<<<NUM_GRAPHS, NT, 0, stream>>>(bufB, batch,
        hW1, hb1, hg1, hbb1, hm1, hv1,
        hW2, hb2, hg2, hbb2, hm2, hv2,
        hW3, hb3, hW4, hb4, out);
}

// Round 10
// 319.937 us; speedup vs baseline: 1.0250x; 1.0250x over previous
//
#include <hip/hip_runtime.h>
#include <hip/hip_bf16.h>
#include <hip/hip_fp16.h>

#define N_NODES 50000
#define N_EDGES 800000
#define NUM_GRAPHS 256
#define D 64
#define EPS 1e-5f
#define N_PART 8
#define PART_SIZE (N_NODES / N_PART)   // 6250
#define SCAT_CHUNKS 512

// ---------------------------------------------------------------------------
// 1) one-pass slotted-CSR build, XCD-partitioned by destination range.
__global__ __launch_bounds__(256) void scatter_cnt_kernel(
        const int* __restrict__ ei, int* __restrict__ cnt,
        int* __restrict__ ssrc, int cap, int E) {
    int p     = blockIdx.x & (N_PART - 1);
    int chunk = blockIdx.x >> 3;
    int per   = (E + SCAT_CHUNKS - 1) / SCAT_CHUNKS;
    int lo    = chunk * per;
    int hi    = lo + per; if (hi > E) hi = E;
    for (int e = lo + threadIdx.x; e < hi; e += 256) {
        int c = ei[E + e];
        if (c / PART_SIZE == p) {
            int r = ei[e];
            int pos = atomicAdd(&cnt[c], 1);
            if (pos < cap) ssrc[(size_t)c * cap + pos] = r;  // P(overflow)~1e-20
        }
    }
}

// 2) Yh[N,64](fp16) = X[N,64](fp32) @ W[64,64] — 64-row tile, 4x4 reg blocking.
//    fp32 accumulate, fp16 store (halves the gather table -> L2-resident).
__global__ __launch_bounds__(256) void gemm64_kernel(const float* __restrict__ X,
                                                     const float* __restrict__ W,
                                                     __half* __restrict__ Yh, int N) {
    __shared__ float Ws[64 * 64];     // row k, col c
    __shared__ float Xs[64 * 65];     // row r (padded), col k
    int base = blockIdx.x * 64;
    for (int i = threadIdx.x; i < 1024; i += 256)
        ((float4*)Ws)[i] = ((const float4*)W)[i];
    for (int i = threadIdx.x; i < 1024; i += 256) {
        int rr = i >> 4, cc = (i & 15) * 4;
        float4 xv = (base + rr < N)
            ? ((const float4*)X)[(size_t)(base + rr) * 16 + (i & 15)]
            : make_float4(0.f, 0.f, 0.f, 0.f);
        float* dst = &Xs[rr * 65 + cc];
        dst[0] = xv.x; dst[1] = xv.y; dst[2] = xv.z; dst[3] = xv.w;
    }
    __syncthreads();
    int rg = (threadIdx.x >> 4) * 4;        // rows rg..rg+3
    int cg = (threadIdx.x & 15) * 4;        // cols cg..cg+3
    float4 a0 = make_float4(0.f,0.f,0.f,0.f);
    float4 a1 = a0, a2 = a0, a3 = a0;
#pragma unroll
    for (int k = 0; k < 64; k++) {
        float4 wv = *(const float4*)&Ws[k * 64 + cg];
        float x0 = Xs[(rg + 0) * 65 + k];
        float x1 = Xs[(rg + 1) * 65 + k];
        float x2 = Xs[(rg + 2) * 65 + k];
        float x3 = Xs[(rg + 3) * 65 + k];
        a0.x += x0*wv.x; a0.y += x0*wv.y; a0.z += x0*wv.z; a0.w += x0*wv.w;
        a1.x += x1*wv.x; a1.y += x1*wv.y; a1.z += x1*wv.z; a1.w += x1*wv.w;
        a2.x += x2*wv.x; a2.y += x2*wv.y; a2.z += x2*wv.z; a2.w += x2*wv.w;
        a3.x += x3*wv.x; a3.y += x3*wv.y; a3.z += x3*wv.z; a3.w += x3*wv.w;
    }
#pragma unroll
    for (int j = 0; j < 4; j++) {
        float4 a = (j == 0) ? a0 : (j == 1) ? a1 : (j == 2) ? a2 : a3;
        int row = base + rg + j;
        if (row < N) {
            __half2 p0 = __floats2half2_rn(a.x, a.y);
            __half2 p1 = __floats2half2_rn(a.z, a.w);
            uint2 v;
            v.x = *(unsigned int*)&p0;
            v.y = *(unsigned int*)&p1;
            *((uint2*)&Yh[(size_t)row * 64 + cg]) = v;
        }
    }
}

// 3) fused slotted-CSR aggregation + self-loop + gcn bias + BN + ReLU.
//    One wave per dest node. Lane = (edge-sub 0..7, feat-group 0..7 of 8 fp16):
//    ONE dwordx4 gather per lane per edge (8 fp16 features), fp32 accumulate.
__global__ __launch_bounds__(256) void agg_bn_kernel(
        const __half* __restrict__ xwh, const int* __restrict__ cnt,
        const int* __restrict__ ssrc, int cap,
        const float* __restrict__ b, const float* __restrict__ g,
        const float* __restrict__ bb, const float* __restrict__ m,
        const float* __restrict__ var,
        float* __restrict__ out, int N) {
    int wave = (blockIdx.x * blockDim.x + threadIdx.x) >> 6;
    int lane = threadIdx.x & 63;
    if (wave >= N) return;
    int c   = wave;
    int sub = lane >> 3;        // which of 8 concurrent edges
    int f2  = lane & 7;         // feature group: feats 8*f2 .. 8*f2+7
    const uint4* xw8 = (const uint4*)xwh;   // 8 halves per uint4, 8 per row
    int n = cnt[c];
    if (n > cap) n = cap;
    size_t base = (size_t)c * cap;
    float dc = rsqrtf((float)n + 1.0f);
    float4 accA = make_float4(0.f, 0.f, 0.f, 0.f);
    float4 accB = accA;
    if (sub == 0) {  // self-loop term dc*xw[c] (final *dc applied below)
        uint4 v = xw8[(size_t)c * 8 + f2];
        __half2* hp = (__half2*)&v;
        float2 q0 = __half22float2(hp[0]), q1 = __half22float2(hp[1]);
        float2 q2 = __half22float2(hp[2]), q3 = __half22float2(hp[3]);
        accA.x = dc * q0.x; accA.y = dc * q0.y; accA.z = dc * q1.x; accA.w = dc * q1.y;
        accB.x = dc * q2.x; accB.y = dc * q2.y; accB.z = dc * q3.x; accB.w = dc * q3.y;
    }
    for (int e0 = 0; e0 < n; e0 += 8) {
        int e = e0 + sub;
        if (e < n) {
            int   r = ssrc[base + e];
            float w = rsqrtf((float)cnt[r] + 1.0f);
            uint4 v = xw8[(size_t)r * 8 + f2];
            __half2* hp = (__half2*)&v;
            float2 q0 = __half22float2(hp[0]), q1 = __half22float2(hp[1]);
            float2 q2 = __half22float2(hp[2]), q3 = __half22float2(hp[3]);
            accA.x += w * q0.x; accA.y += w * q0.y;
            accA.z += w * q1.x; accA.w += w * q1.y;
            accB.x += w * q2.x; accB.y += w * q2.y;
            accB.z += w * q3.x; accB.w += w * q3.y;
        }
    }
    // reduce the 8 sub-accumulators (lanes differing in bits 3,4,5)
#pragma unroll
    for (int off = 8; off < 64; off <<= 1) {
        accA.x += __shfl_xor(accA.x, off, 64); accA.y += __shfl_xor(accA.y, off, 64);
        accA.z += __shfl_xor(accA.z, off, 64); accA.w += __shfl_xor(accA.w, off, 64);
        accB.x += __shfl_xor(accB.x, off, 64); accB.y += __shfl_xor(accB.y, off, 64);
        accB.z += __shfl_xor(accB.z, off, 64); accB.w += __shfl_xor(accB.w, off, 64);
    }
    if (sub == 0) {
        const float4* b4v  = (const float4*)b;
        const float4* m4v  = (const float4*)m;
        const float4* v4v  = (const float4*)var;
        const float4* g4v  = (const float4*)g;
        const float4* bb4v = (const float4*)bb;
#pragma unroll
        for (int half = 0; half < 2; half++) {
            int i4 = 2 * f2 + half;
            float4 acc = half ? accB : accA;
            float4 b4 = b4v[i4], m4 = m4v[i4], v4 = v4v[i4], g4 = g4v[i4], bb4 = bb4v[i4];
            float4 h;
            h.x = (acc.x * dc + b4.x - m4.x) * (1.0f / sqrtf(v4.x + EPS)) * g4.x + bb4.x;
            h.y = (acc.y * dc + b4.y - m4.y) * (1.0f / sqrtf(v4.y + EPS)) * g4.y + bb4.y;
            h.z = (acc.z * dc + b4.z - m4.z) * (1.0f / sqrtf(v4.z + EPS)) * g4.z + bb4.z;
            h.w = (acc.w * dc + b4.w - m4.w) * (1.0f / sqrtf(v4.w + EPS)) * g4.w + bb4.w;
            h.x = h.x > 0.f ? h.x : 0.f;
            h.y = h.y > 0.f ? h.y : 0.f;
            h.z = h.z > 0.f ? h.z : 0.f;
            h.w = h.w > 0.f ? h.w : 0.f;
            ((float4*)out)[(size_t)c * 16 + i4] = h;
        }
    }
}

// 4) fused mean-pool (via sorted-batch binary search) + full MLP head.
__global__ __launch_bounds__(256) void pool_head_kernel(
        const float* __restrict__ h, const int* __restrict__ batch,
        const float* __restrict__ hW1, const float* __restrict__ hb1,
        const float* __restrict__ hg1, const float* __restrict__ hbb1,
        const float* __restrict__ hm1, const float* __restrict__ hv1,
        const float* __restrict__ hW2, const float* __restrict__ hb2,
        const float* __restrict__ hg2, const float* __restrict__ hbb2,
        const float* __restrict__ hm2, const float* __restrict__ hv2,
        const float* __restrict__ hW3, const float* __restrict__ hb3,
        const float* __restrict__ hW4, const float* __restrict__ hb4,
        float* __restrict__ out) {
    __shared__ int se[2];
    __shared__ float red[256];
    __shared__ float pooled[64];
    __shared__ float z1[256];
    __shared__ float z2[128];
    __shared__ float z3[64];
    int g = blockIdx.x;
    int t = threadIdx.x;
    if (t < 2) {
        int target = g + t;
        int lo = 0, hi = N_NODES;
        while (lo < hi) {
            int mid = (lo + hi) >> 1;
            if (batch[mid] < target) lo = mid + 1; else hi = mid;
        }
        se[t] = lo;
    }
    __syncthreads();
    int start = se[0], end = se[1];
    {   // mean pool: 4 row-groups x 64 features
        int f = t & 63, rg = t >> 6;
        float part = 0.0f;
        for (int r = start + rg; r < end; r += 4) part += h[(size_t)r * 64 + f];
        red[t] = part;
        __syncthreads();
        if (t < 64) {
            float s = red[t] + red[t + 64] + red[t + 128] + red[t + 192];
            float cnt = (float)(end - start);
            cnt = cnt > 1.0f ? cnt : 1.0f;
            pooled[t] = s / cnt;
        }
    }
    __syncthreads();
    {   // layer 1: 64 -> 256, BN + relu
        float acc = hb1[t];
#pragma unroll
        for (int k = 0; k < 64; k++) acc += pooled[k] * hW1[k * 256 + t];
        acc = (acc - hm1[t]) * (1.0f / sqrtf(hv1[t] + EPS)) * hg1[t] + hbb1[t];
        z1[t] = acc > 0.0f ? acc : 0.0f;
    }
    __syncthreads();
    if (t < 128) {  // layer 2: 256 -> 128, BN + relu
        float acc = hb2[t];
#pragma unroll 8
        for (int k = 0; k < 256; k++) acc += z1[k] * hW2[k * 128 + t];
        acc = (acc - hm2[t]) * (1.0f / sqrtf(hv2[t] + EPS)) * hg2[t] + hbb2[t];
        z2[t] = acc > 0.0f ? acc : 0.0f;
    }
    __syncthreads();
    if (t < 64) {   // layer 3: 128 -> 64, relu
        float acc = hb3[t];
#pragma unroll 8
        for (int k = 0; k < 128; k++) acc += z2[k] * hW3[k * 64 + t];
        z3[t] = acc > 0.0f ? acc : 0.0f;
    }
    __syncthreads();
    if (t < 64) {   // layer 4: 64 -> 1, wave reduce
        float v = z3[t] * hW4[t];
        for (int off = 32; off > 0; off >>= 1) v += __shfl_down(v, off, 64);
        if (t == 0) out[g] = v + hb4[0];
    }
}

extern "C" void kernel_launch(void* const* d_in, const int* in_sizes, int n_in,
                              void* d_out, int out_size, void* d_ws, size_t ws_size,
                              hipStream_t stream) {
    const float* x     = (const float*)d_in[0];
    const int*   ei    = (const int*)d_in[1];   // [2, E] int32
    const int*   batch = (const int*)d_in[2];
    const float* W0 = (const float*)d_in[3];
    const float* b0 = (const float*)d_in[4];
    const float* g0 = (const float*)d_in[5];
    const float* bb0 = (const float*)d_in[6];
    const float* m0 = (const float*)d_in[7];
    const float* v0 = (const float*)d_in[8];
    const float* W1 = (const float*)d_in[9];
    const float* b1 = (const float*)d_in[10];
    const float* g1 = (const float*)d_in[11];
    const float* bb1 = (const float*)d_in[12];
    const float* m1 = (const float*)d_in[13];
    const float* v1 = (const float*)d_in[14];
    const float* hW1 = (const float*)d_in[15];
    const float* hb1 = (const float*)d_in[16];
    const float* hg1 = (const float*)d_in[17];
    const float* hbb1 = (const float*)d_in[18];
    const float* hm1 = (const float*)d_in[19];
    const float* hv1 = (const float*)d_in[20];
    const float* hW2 = (const float*)d_in[21];
    const float* hb2 = (const float*)d_in[22];
    const float* hg2 = (const float*)d_in[23];
    const float* hbb2 = (const float*)d_in[24];
    const float* hm2 = (const float*)d_in[25];
    const float* hv2 = (const float*)d_in[26];
    const float* hW3 = (const float*)d_in[27];
    const float* hb3 = (const float*)d_in[28];
    const float* hW4 = (const float*)d_in[29];
    const float* hb4 = (const float*)d_in[30];
    float* out = (float*)d_out;

    // workspace layout (d_ws is 16B-aligned)
    // bufA region: fp16 gather table (N*64 halves = 6.4MB; region sized as N*64 floats)
    float*  bufA = (float*)d_ws;                         // N*64 floats (table uses half)
    __half* xwh  = (__half*)bufA;
    float*  bufB = bufA + (size_t)N_NODES * D;           // N*64 floats (node features)
    int*    cnt  = (int*)(bufB + (size_t)N_NODES * D);   // N
    int*    ssrc = cnt + N_NODES;                        // N*cap

    // pick the slot capacity from remaining workspace (prefer 64; deg~Poisson(16))
    size_t used  = ((size_t)2 * N_NODES * D + N_NODES) * 4;
    int cap = 64;
    if (ws_size >= used) {
        size_t avail = (ws_size - used) / ((size_t)N_NODES * 4);
        if (avail < (size_t)cap) cap = (int)avail & ~3;  // multiple of 4
    } else {
        cap = 0;  // should not happen; avoids OOB
    }

    const int NT = 256;
    hipMemsetAsync(cnt, 0, (size_t)N_NODES * 4, stream);

    // one-pass XCD-partitioned slotted-CSR build
    scatter_cnt_kernel<<<SCAT_CHUNKS * N_PART, NT, 0, stream>>>(ei, cnt, ssrc, cap, N_EDGES);

    // layer 0
    gemm64_kernel<<<(N_NODES + 63) / 64, NT, 0, stream>>>(x, W0, xwh, N_NODES);
    agg_bn_kernel<<<(N_NODES * 64 + NT - 1) / NT, NT, 0, stream>>>(
        xwh, cnt, ssrc, cap, b0, g0, bb0, m0, v0, bufB, N_NODES);

    // layer 1
    gemm64_kernel<<<(N_NODES + 63) / 64, NT, 0, stream>>>(bufB, W1, xwh, N_NODES);
    agg_bn_kernel<<<(N_NODES * 64 + NT - 1) / NT, NT, 0, stream>>>(
        xwh, cnt, ssrc, cap, b1, g1, bb1, m1, v1, bufB, N_NODES);

    // mean pool + MLP head (fused)
    pool_head_kernel<<<NUM_GRAPHS, NT, 0, stream>>>(bufB, batch,
        hW1, hb1, hg1, hbb1, hm1, hv1,
        hW2, hb2, hg2, hbb2, hm2, hv2,
        hW3, hb3, hW4, hb4, out);
}